// Round 8
// baseline (921.400 us; speedup 1.0000x reference)
//
#include <hip/hip_runtime.h>

#define BB  4
#define SS  512
#define JJ  24
#define HH  128
#define NHH 8
#define HSS 16

// ---------- bf16 helpers (LDS compression only; all math fp32) ----------
__device__ __forceinline__ unsigned short f2b(float f) {
    unsigned u; __builtin_memcpy(&u, &f, 4);
    u += 0x7fffu + ((u >> 16) & 1u);          // RNE
    return (unsigned short)(u >> 16);
}
__device__ __forceinline__ unsigned pk2(float a, float b) {
    return (unsigned)f2b(a) | ((unsigned)f2b(b) << 16);
}
__device__ __forceinline__ void unpack2(unsigned u, float& lo, float& hi) {
    unsigned a = u << 16, b = u & 0xffff0000u;
    __builtin_memcpy(&lo, &a, 4); __builtin_memcpy(&hi, &b, 4);
}
__device__ __forceinline__ void unpack16(const uint4 w0, const uint4 w1, float* f) {
    unpack2(w0.x, f[0],  f[1]);  unpack2(w0.y, f[2],  f[3]);
    unpack2(w0.z, f[4],  f[5]);  unpack2(w0.w, f[6],  f[7]);
    unpack2(w1.x, f[8],  f[9]);  unpack2(w1.y, f[10], f[11]);
    unpack2(w1.z, f[12], f[13]); unpack2(w1.w, f[14], f[15]);
}
__device__ __forceinline__ void fma16v(const uint4 w0, const uint4 w1, float xv, float* acc) {
    float wf[16];
    unpack16(w0, w1, wf);
#pragma unroll
    for (int d = 0; d < 16; ++d) acc[d] = fmaf(xv, wf[d], acc[d]);
}

// ---------- LN param staging with fallback (gamma=1, beta=0) ----------
__global__ __launch_bounds__(128) void ln_param_kernel(
        const float* __restrict__ g, const float* __restrict__ b,
        float* __restrict__ gws, float* __restrict__ bws) {
    int k = threadIdx.x;
    gws[k] = g ? g[k] : 1.0f;
    bws[k] = b ? b[k] : 0.0f;
}

// ---------- kernel A: fused QKV projection + causal attention per (b,n,j) ----------
// LDS: KVs interleaved bf16 32 KB + weights bf16 12 KB = 44 KB -> 3 blocks/CU.
// Softmax without online max: scores are O(sigma~1); exp(s) clamped at 60 is
// mathematically identical to softmax (shift-invariant, no shift applied).
__global__ __launch_bounds__(256, 3) void qkv_attn_kernel(
        const float* __restrict__ x,
        const float* __restrict__ qm,
        const float* __restrict__ km,
        const float* __restrict__ vm,
        float* __restrict__ AO) {
    __shared__ __align__(16) unsigned short KVs[SS][32];  // 32 KB: [0:16)=K, [16:32)=V bf16
    __shared__ __align__(16) unsigned short Wq[HH * HSS]; // 4 KB bf16
    __shared__ __align__(16) unsigned short Wk[HH * HSS]; // 4 KB
    __shared__ __align__(16) unsigned short Wv[HH * HSS]; // 4 KB

    int tid = threadIdx.x;
    int blk = blockIdx.x;           // (b*NH+n)*J + j
    int j  = blk % JJ;
    int nb = blk / JJ;
    int n  = nb % NHH;
    int b  = nb / NHH;

    size_t wbase = (size_t)(n * JJ + j) * HH * HSS;
    const float* gq = qm + wbase;
    const float* gk = km + wbase;
    const float* gv = vm + wbase;
    for (int i = tid; i < HH * HSS; i += 256) {
        Wq[i] = f2b(gq[i]); Wk[i] = f2b(gk[i]); Wv[i] = f2b(gv[i]);
    }
    __syncthreads();

    int r1 = tid;            // rows 0..255
    int r2 = SS - 1 - tid;   // rows 511..256
    float q1[HSS], q2[HSS];
    const uint4* wq4 = (const uint4*)Wq;   // row h = wq4[2h], wq4[2h+1]
    const uint4* wk4 = (const uint4*)Wk;
    const uint4* wv4 = (const uint4*)Wv;

    for (int rr = 0; rr < 2; ++rr) {
        int r = rr ? r2 : r1;
        float qa[16], ka[16], va[16];
#pragma unroll
        for (int d = 0; d < 16; ++d) { qa[d] = 0.f; ka[d] = 0.f; va[d] = 0.f; }
        const float4* xp = (const float4*)(x + ((size_t)((b * SS + r) * JJ + j)) * HH);
        for (int h8 = 0; h8 < HH / 8; ++h8) {
            float4 xa = xp[2 * h8], xb = xp[2 * h8 + 1];
            float xs[8] = {xa.x, xa.y, xa.z, xa.w, xb.x, xb.y, xb.z, xb.w};
#pragma unroll
            for (int hh = 0; hh < 8; ++hh) {
                int h = h8 * 8 + hh;
                float xv = xs[hh];
                fma16v(wq4[2 * h], wq4[2 * h + 1], xv, qa);
                fma16v(wk4[2 * h], wk4[2 * h + 1], xv, ka);
                fma16v(wv4[2 * h], wv4[2 * h + 1], xv, va);
            }
        }
        // interleaved K|V bf16 row (4 x b128 write)
        uint4* dst = (uint4*)KVs[r];
        dst[0] = make_uint4(pk2(ka[0], ka[1]),  pk2(ka[2], ka[3]),
                            pk2(ka[4], ka[5]),  pk2(ka[6], ka[7]));
        dst[1] = make_uint4(pk2(ka[8], ka[9]),  pk2(ka[10], ka[11]),
                            pk2(ka[12], ka[13]), pk2(ka[14], ka[15]));
        dst[2] = make_uint4(pk2(va[0], va[1]),  pk2(va[2], va[3]),
                            pk2(va[4], va[5]),  pk2(va[6], va[7]));
        dst[3] = make_uint4(pk2(va[8], va[9]),  pk2(va[10], va[11]),
                            pk2(va[12], va[13]), pk2(va[14], va[15]));
        float* qd = rr ? q2 : q1;
#pragma unroll
        for (int d = 0; d < 16; ++d) qd[d] = qa[d] * 0.25f;   // fold 1/sqrt(HS)
    }
    __syncthreads();

    float o1[16], o2[16];
#pragma unroll
    for (int d = 0; d < 16; ++d) { o1[d] = 0.f; o2[d] = 0.f; }
    float l1 = 0.f, l2 = 0.f;

    // phase 1: tt in [0,256): r2 >= 256 > tt always active; r1 conditional
    for (int tt = 0; tt < 256; ++tt) {
        const uint4* kv = (const uint4*)KVs[tt];
        uint4 u0 = kv[0], u1 = kv[1], u2 = kv[2], u3 = kv[3];
        float kf[16], vf[16];
        unpack16(u0, u1, kf);
        unpack16(u2, u3, vf);
        if (tt <= r1) {
            float dp = 0.f;
#pragma unroll
            for (int d = 0; d < 16; ++d) dp = fmaf(q1[d], kf[d], dp);
            float p = __expf(fminf(dp, 60.f));
            l1 += p;
#pragma unroll
            for (int d = 0; d < 16; ++d) o1[d] = fmaf(p, vf[d], o1[d]);
        }
        {
            float dp = 0.f;
#pragma unroll
            for (int d = 0; d < 16; ++d) dp = fmaf(q2[d], kf[d], dp);
            float p = __expf(fminf(dp, 60.f));
            l2 += p;
#pragma unroll
            for (int d = 0; d < 16; ++d) o2[d] = fmaf(p, vf[d], o2[d]);
        }
    }
    // phase 2: tt in [256,512): r1 < 256 never active; r2 conditional
    for (int tt = 256; tt < SS; ++tt) {
        const uint4* kv = (const uint4*)KVs[tt];
        uint4 u0 = kv[0], u1 = kv[1], u2 = kv[2], u3 = kv[3];
        if (tt <= r2) {
            float kf[16], vf[16];
            unpack16(u0, u1, kf);
            unpack16(u2, u3, vf);
            float dp = 0.f;
#pragma unroll
            for (int d = 0; d < 16; ++d) dp = fmaf(q2[d], kf[d], dp);
            float p = __expf(fminf(dp, 60.f));
            l2 += p;
#pragma unroll
            for (int d = 0; d < 16; ++d) o2[d] = fmaf(p, vf[d], o2[d]);
        }
    }
    // AO layout: (b, s, j, n*HS+d) fp32
    float inv1 = 1.0f / l1, inv2 = 1.0f / l2;
    float* out1 = AO + ((size_t)((b * SS + r1) * JJ + j)) * HH + n * HSS;
    float* out2 = AO + ((size_t)((b * SS + r2) * JJ + j)) * HH + n * HSS;
#pragma unroll
    for (int d = 0; d < 16; ++d) {
        out1[d] = o1[d] * inv1;
        out2[d] = o2[d] * inv2;
    }
}

// ---------- kernel B: output projection + residual + LayerNorm (fp32 out) ----------
__global__ __launch_bounds__(256) void proj_ln_kernel(
        const float* __restrict__ AO, const float* __restrict__ x,
        const float* __restrict__ proj,
        const float* __restrict__ gamma, const float* __restrict__ beta,
        float* __restrict__ out) {
    __shared__ float aoS[8][HH];        // 4 KB
    __shared__ float meanS[8], rstdS[8];
    int blk   = blockIdx.x;             // (b*J + j)*(S/8) + stile
    int stile = blk % (SS / 8);
    int t2    = blk / (SS / 8);
    int j = t2 % JJ;
    int b = t2 / JJ;
    int s0  = stile * 8;
    int tid = threadIdx.x;

    for (int i = tid; i < 8 * HH; i += 256) {
        int lr = i >> 7, k2 = i & 127;
        aoS[lr][k2] = AO[((size_t)((b * SS + s0 + lr) * JJ + j)) * HH + k2];
    }
    __syncthreads();

    int k  = tid & 127;
    int rg = tid >> 7;                  // rows rg, rg+2, rg+4, rg+6
    float acc[4] = {0.f, 0.f, 0.f, 0.f};
    const float* pjp = proj + (size_t)j * HH * HH;
    for (int h = 0; h < HH; ++h) {
        float w = pjp[h * HH + k];      // proj[j,h,k], coalesced over k
#pragma unroll
        for (int i = 0; i < 4; ++i) acc[i] = fmaf(aoS[rg + 2 * i][h], w, acc[i]);
    }
    float val[4];
#pragma unroll
    for (int i = 0; i < 4; ++i) {
        int srow = s0 + rg + 2 * i;
        val[i] = acc[i] + x[((size_t)((b * SS + srow) * JJ + j)) * HH + k];
    }
    __syncthreads();                    // everyone done reading aoS
#pragma unroll
    for (int i = 0; i < 4; ++i) aoS[rg + 2 * i][k] = val[i];
    __syncthreads();

    // LN reductions: 32 lanes per row
    int row = tid >> 5, l32 = tid & 31;
    float s1 = 0.f, s2 = 0.f;
#pragma unroll
    for (int c = 0; c < 4; ++c) {
        float v = aoS[row][l32 + 32 * c];
        s1 += v; s2 += v * v;
    }
#pragma unroll
    for (int mdel = 16; mdel >= 1; mdel >>= 1) {
        s1 += __shfl_xor(s1, mdel, 64);
        s2 += __shfl_xor(s2, mdel, 64);
    }
    if (l32 == 0) {
        float mu  = s1 * (1.0f / 128.0f);
        float var = s2 * (1.0f / 128.0f) - mu * mu;
        meanS[row] = mu;
        rstdS[row] = rsqrtf(var + 1e-5f);
    }
    __syncthreads();
    float g  = gamma[k];
    float bt = beta[k];
#pragma unroll
    for (int i = 0; i < 4; ++i) {
        int lr = rg + 2 * i;
        float o = (val[i] - meanS[lr]) * rstdS[lr] * g + bt;
        out[((size_t)((b * SS + s0 + lr) * JJ + j)) * HH + k] = o;
    }
}

extern "C" void kernel_launch(void* const* d_in, const int* in_sizes, int n_in,
                              void* d_out, int out_size, void* d_ws, size_t ws_size,
                              hipStream_t stream) {
    const int NX  = BB * SS * JJ * HH;     // 6,291,456
    const int NMK = SS * SS;               // 262,144
    const int NW  = NHH * JJ * HH * HSS;   // 393,216 (== JJ*HH*HH)
    const float* x = nullptr;
    const float* w4[4] = {nullptr, nullptr, nullptr, nullptr};
    const float* p128[2] = {nullptr, nullptr};
    int nW = 0, n128 = 0;
    for (int i = 0; i < n_in; ++i) {
        int s = in_sizes[i];
        const float* p = (const float*)d_in[i];
        if      (s == NX)   { if (!x) x = p; }
        else if (s == NMK)  { /* causal mask: implemented directly */ }
        else if (s == NW)   { if (nW < 4)  w4[nW++] = p; }
        else if (s == HH)   { if (n128 < 2) p128[n128++] = p; }
    }
    const float* qm = w4[0];
    const float* km = w4[1];
    const float* vm = w4[2];
    const float* pj = w4[3];
    float* out = (float*)d_out;            // reference output dtype: float32

    // ws layout: AO fp32 (25.2 MB) + gamma(128) + beta(128)
    float* AO = (float*)d_ws;
    float* gb = AO + (size_t)NX;
    float* bb = gb + HH;

    ln_param_kernel<<<1, 128, 0, stream>>>(p128[0], p128[1], gb, bb);
    qkv_attn_kernel<<<BB * NHH * JJ, 256, 0, stream>>>(x, qm, km, vm, AO);
    proj_ln_kernel<<<BB * JJ * (SS / 8), 256, 0, stream>>>(AO, x, pj, gb, bb, out);
}

// Round 9
// 446.601 us; speedup vs baseline: 2.0631x; 2.0631x over previous
//
#include <hip/hip_runtime.h>

#define BB  4
#define SS  512
#define JJ  24
#define HH  128
#define NHH 8
#define HSS 16

// ---------- bf16 helpers (LDS compression only; all math fp32) ----------
__device__ __forceinline__ unsigned short f2b(float f) {
    unsigned u; __builtin_memcpy(&u, &f, 4);
    u += 0x7fffu + ((u >> 16) & 1u);          // RNE
    return (unsigned short)(u >> 16);
}
__device__ __forceinline__ unsigned pk2(float a, float b) {
    return (unsigned)f2b(a) | ((unsigned)f2b(b) << 16);
}
__device__ __forceinline__ void unpack2(unsigned u, float& lo, float& hi) {
    unsigned a = u << 16, b = u & 0xffff0000u;
    __builtin_memcpy(&lo, &a, 4); __builtin_memcpy(&hi, &b, 4);
}
__device__ __forceinline__ void unpack16(const uint4 w0, const uint4 w1, float* f) {
    unpack2(w0.x, f[0],  f[1]);  unpack2(w0.y, f[2],  f[3]);
    unpack2(w0.z, f[4],  f[5]);  unpack2(w0.w, f[6],  f[7]);
    unpack2(w1.x, f[8],  f[9]);  unpack2(w1.y, f[10], f[11]);
    unpack2(w1.z, f[12], f[13]); unpack2(w1.w, f[14], f[15]);
}
__device__ __forceinline__ void fma16v(const uint4 w0, const uint4 w1, float xv, float* acc) {
    float wf[16];
    unpack16(w0, w1, wf);
#pragma unroll
    for (int d = 0; d < 16; ++d) acc[d] = fmaf(xv, wf[d], acc[d]);
}

// ---------- LN param staging with fallback (gamma=1, beta=0) ----------
__global__ __launch_bounds__(128) void ln_param_kernel(
        const float* __restrict__ g, const float* __restrict__ b,
        float* __restrict__ gws, float* __restrict__ bws) {
    int k = threadIdx.x;
    gws[k] = g ? g[k] : 1.0f;
    bws[k] = b ? b[k] : 0.0f;
}

// ---------- kernel A: fused QKV projection + causal attention per (b,n,j) ----------
// LDS: KVs interleaved bf16 32 KB + weights bf16 12 KB = 44 KB.
// launch_bounds(256,2): VGPR cap 256 — the kernel's ~200 live regs fit with NO
// scratch spill. (256,3) capped at 84 and spilled the hot loop to HBM: 3.1 GB
// traffic, 820 us — measured round 8. Do not tighten this again.
__global__ __launch_bounds__(256, 2) void qkv_attn_kernel(
        const float* __restrict__ x,
        const float* __restrict__ qm,
        const float* __restrict__ km,
        const float* __restrict__ vm,
        float* __restrict__ AO) {
    __shared__ __align__(16) unsigned short KVs[SS][32];  // 32 KB: [0:16)=K, [16:32)=V bf16
    __shared__ __align__(16) unsigned short Wq[HH * HSS]; // 4 KB bf16
    __shared__ __align__(16) unsigned short Wk[HH * HSS]; // 4 KB
    __shared__ __align__(16) unsigned short Wv[HH * HSS]; // 4 KB

    int tid = threadIdx.x;
    int blk = blockIdx.x;           // (b*NH+n)*J + j
    int j  = blk % JJ;
    int nb = blk / JJ;
    int n  = nb % NHH;
    int b  = nb / NHH;

    size_t wbase = (size_t)(n * JJ + j) * HH * HSS;
    const float* gq = qm + wbase;
    const float* gk = km + wbase;
    const float* gv = vm + wbase;
    for (int i = tid; i < HH * HSS; i += 256) {
        Wq[i] = f2b(gq[i]); Wk[i] = f2b(gk[i]); Wv[i] = f2b(gv[i]);
    }
    __syncthreads();

    int r1 = tid;            // rows 0..255
    int r2 = SS - 1 - tid;   // rows 511..256
    float q1[HSS], q2[HSS];
    const uint4* wq4 = (const uint4*)Wq;   // row h = wq4[2h], wq4[2h+1]
    const uint4* wk4 = (const uint4*)Wk;
    const uint4* wv4 = (const uint4*)Wv;

    for (int rr = 0; rr < 2; ++rr) {
        int r = rr ? r2 : r1;
        float qa[16], ka[16], va[16];
#pragma unroll
        for (int d = 0; d < 16; ++d) { qa[d] = 0.f; ka[d] = 0.f; va[d] = 0.f; }
        const float4* xp = (const float4*)(x + ((size_t)((b * SS + r) * JJ + j)) * HH);
        for (int h8 = 0; h8 < HH / 8; ++h8) {
            float4 xa = xp[2 * h8], xb = xp[2 * h8 + 1];
            float xs[8] = {xa.x, xa.y, xa.z, xa.w, xb.x, xb.y, xb.z, xb.w};
#pragma unroll
            for (int hh = 0; hh < 8; ++hh) {
                int h = h8 * 8 + hh;
                float xv = xs[hh];
                fma16v(wq4[2 * h], wq4[2 * h + 1], xv, qa);
                fma16v(wk4[2 * h], wk4[2 * h + 1], xv, ka);
                fma16v(wv4[2 * h], wv4[2 * h + 1], xv, va);
            }
        }
        // interleaved K|V bf16 row (4 x b128 write)
        uint4* dst = (uint4*)KVs[r];
        dst[0] = make_uint4(pk2(ka[0], ka[1]),  pk2(ka[2], ka[3]),
                            pk2(ka[4], ka[5]),  pk2(ka[6], ka[7]));
        dst[1] = make_uint4(pk2(ka[8], ka[9]),  pk2(ka[10], ka[11]),
                            pk2(ka[12], ka[13]), pk2(ka[14], ka[15]));
        dst[2] = make_uint4(pk2(va[0], va[1]),  pk2(va[2], va[3]),
                            pk2(va[4], va[5]),  pk2(va[6], va[7]));
        dst[3] = make_uint4(pk2(va[8], va[9]),  pk2(va[10], va[11]),
                            pk2(va[12], va[13]), pk2(va[14], va[15]));
        float* qd = rr ? q2 : q1;
#pragma unroll
        for (int d = 0; d < 16; ++d) qd[d] = qa[d] * 0.25f;   // fold 1/sqrt(HS)
    }
    __syncthreads();

    float o1[16], o2[16];
#pragma unroll
    for (int d = 0; d < 16; ++d) { o1[d] = 0.f; o2[d] = 0.f; }
    float l1 = 0.f, l2 = 0.f;

    // phase 1: tt in [0,256): r2 >= 256 > tt always active; r1 conditional
    for (int tt = 0; tt < 256; ++tt) {
        const uint4* kv = (const uint4*)KVs[tt];
        uint4 u0 = kv[0], u1 = kv[1], u2 = kv[2], u3 = kv[3];
        float kf[16], vf[16];
        unpack16(u0, u1, kf);
        unpack16(u2, u3, vf);
        if (tt <= r1) {
            float dp = 0.f;
#pragma unroll
            for (int d = 0; d < 16; ++d) dp = fmaf(q1[d], kf[d], dp);
            float p = __expf(fminf(dp, 60.f));
            l1 += p;
#pragma unroll
            for (int d = 0; d < 16; ++d) o1[d] = fmaf(p, vf[d], o1[d]);
        }
        {
            float dp = 0.f;
#pragma unroll
            for (int d = 0; d < 16; ++d) dp = fmaf(q2[d], kf[d], dp);
            float p = __expf(fminf(dp, 60.f));
            l2 += p;
#pragma unroll
            for (int d = 0; d < 16; ++d) o2[d] = fmaf(p, vf[d], o2[d]);
        }
    }
    // phase 2: tt in [256,512): r1 < 256 never active; r2 conditional.
    // Loads inside the branch so fully-drained waves skip via s_cbranch_execz.
    for (int tt = 256; tt < SS; ++tt) {
        if (tt <= r2) {
            const uint4* kv = (const uint4*)KVs[tt];
            uint4 u0 = kv[0], u1 = kv[1], u2 = kv[2], u3 = kv[3];
            float kf[16], vf[16];
            unpack16(u0, u1, kf);
            unpack16(u2, u3, vf);
            float dp = 0.f;
#pragma unroll
            for (int d = 0; d < 16; ++d) dp = fmaf(q2[d], kf[d], dp);
            float p = __expf(fminf(dp, 60.f));
            l2 += p;
#pragma unroll
            for (int d = 0; d < 16; ++d) o2[d] = fmaf(p, vf[d], o2[d]);
        }
    }
    // AO layout: (b, s, j, n*HS+d) fp32
    float inv1 = 1.0f / l1, inv2 = 1.0f / l2;
    float* out1 = AO + ((size_t)((b * SS + r1) * JJ + j)) * HH + n * HSS;
    float* out2 = AO + ((size_t)((b * SS + r2) * JJ + j)) * HH + n * HSS;
#pragma unroll
    for (int d = 0; d < 16; ++d) {
        out1[d] = o1[d] * inv1;
        out2[d] = o2[d] * inv2;
    }
}

// ---------- kernel B: output projection + residual + LayerNorm (fp32 out) ----------
__global__ __launch_bounds__(256) void proj_ln_kernel(
        const float* __restrict__ AO, const float* __restrict__ x,
        const float* __restrict__ proj,
        const float* __restrict__ gamma, const float* __restrict__ beta,
        float* __restrict__ out) {
    __shared__ float aoS[8][HH];        // 4 KB
    __shared__ float meanS[8], rstdS[8];
    int blk   = blockIdx.x;             // (b*J + j)*(S/8) + stile
    int stile = blk % (SS / 8);
    int t2    = blk / (SS / 8);
    int j = t2 % JJ;
    int b = t2 / JJ;
    int s0  = stile * 8;
    int tid = threadIdx.x;

    for (int i = tid; i < 8 * HH; i += 256) {
        int lr = i >> 7, k2 = i & 127;
        aoS[lr][k2] = AO[((size_t)((b * SS + s0 + lr) * JJ + j)) * HH + k2];
    }
    __syncthreads();

    int k  = tid & 127;
    int rg = tid >> 7;                  // rows rg, rg+2, rg+4, rg+6
    float acc[4] = {0.f, 0.f, 0.f, 0.f};
    const float* pjp = proj + (size_t)j * HH * HH;
    for (int h = 0; h < HH; ++h) {
        float w = pjp[h * HH + k];      // proj[j,h,k], coalesced over k
#pragma unroll
        for (int i = 0; i < 4; ++i) acc[i] = fmaf(aoS[rg + 2 * i][h], w, acc[i]);
    }
    float val[4];
#pragma unroll
    for (int i = 0; i < 4; ++i) {
        int srow = s0 + rg + 2 * i;
        val[i] = acc[i] + x[((size_t)((b * SS + srow) * JJ + j)) * HH + k];
    }
    __syncthreads();                    // everyone done reading aoS
#pragma unroll
    for (int i = 0; i < 4; ++i) aoS[rg + 2 * i][k] = val[i];
    __syncthreads();

    // LN reductions: 32 lanes per row
    int row = tid >> 5, l32 = tid & 31;
    float s1 = 0.f, s2 = 0.f;
#pragma unroll
    for (int c = 0; c < 4; ++c) {
        float v = aoS[row][l32 + 32 * c];
        s1 += v; s2 += v * v;
    }
#pragma unroll
    for (int mdel = 16; mdel >= 1; mdel >>= 1) {
        s1 += __shfl_xor(s1, mdel, 64);
        s2 += __shfl_xor(s2, mdel, 64);
    }
    if (l32 == 0) {
        float mu  = s1 * (1.0f / 128.0f);
        float var = s2 * (1.0f / 128.0f) - mu * mu;
        meanS[row] = mu;
        rstdS[row] = rsqrtf(var + 1e-5f);
    }
    __syncthreads();
    float g  = gamma[k];
    float bt = beta[k];
#pragma unroll
    for (int i = 0; i < 4; ++i) {
        int lr = rg + 2 * i;
        float o = (val[i] - meanS[lr]) * rstdS[lr] * g + bt;
        out[((size_t)((b * SS + s0 + lr) * JJ + j)) * HH + k] = o;
    }
}

extern "C" void kernel_launch(void* const* d_in, const int* in_sizes, int n_in,
                              void* d_out, int out_size, void* d_ws, size_t ws_size,
                              hipStream_t stream) {
    const int NX  = BB * SS * JJ * HH;     // 6,291,456
    const int NMK = SS * SS;               // 262,144
    const int NW  = NHH * JJ * HH * HSS;   // 393,216 (== JJ*HH*HH)
    const float* x = nullptr;
    const float* w4[4] = {nullptr, nullptr, nullptr, nullptr};
    const float* p128[2] = {nullptr, nullptr};
    int nW = 0, n128 = 0;
    for (int i = 0; i < n_in; ++i) {
        int s = in_sizes[i];
        const float* p = (const float*)d_in[i];
        if      (s == NX)   { if (!x) x = p; }
        else if (s == NMK)  { /* causal mask: implemented directly */ }
        else if (s == NW)   { if (nW < 4)  w4[nW++] = p; }
        else if (s == HH)   { if (n128 < 2) p128[n128++] = p; }
    }
    const float* qm = w4[0];
    const float* km = w4[1];
    const float* vm = w4[2];
    const float* pj = w4[3];
    float* out = (float*)d_out;            // reference output dtype: float32

    // ws layout: AO fp32 (25.2 MB) + gamma(128) + beta(128)
    float* AO = (float*)d_ws;
    float* gb = AO + (size_t)NX;
    float* bb = gb + HH;

    ln_param_kernel<<<1, 128, 0, stream>>>(p128[0], p128[1], gb, bb);
    qkv_attn_kernel<<<BB * NHH * JJ, 256, 0, stream>>>(x, qm, km, vm, AO);
    proj_ln_kernel<<<BB * JJ * (SS / 8), 256, 0, stream>>>(AO, x, pj, gb, bb, out);
}

// Round 10
// 344.697 us; speedup vs baseline: 2.6731x; 1.2956x over previous
//
#include <hip/hip_runtime.h>

#define BB  4
#define SS  512
#define JJ  24
#define HH  128
#define NHH 8
#define HSS 16

typedef __attribute__((ext_vector_type(8))) short bf16x8;
typedef __attribute__((ext_vector_type(4))) float f32x4;

// ---------- bf16 helpers (storage compression only; math fp32/MFMA) ----------
__device__ __forceinline__ unsigned short f2b(float f) {
    unsigned u; __builtin_memcpy(&u, &f, 4);
    u += 0x7fffu + ((u >> 16) & 1u);          // RNE
    return (unsigned short)(u >> 16);
}
__device__ __forceinline__ unsigned pk2(float a, float b) {
    return (unsigned)f2b(a) | ((unsigned)f2b(b) << 16);
}
__device__ __forceinline__ void unpack2(unsigned u, float& lo, float& hi) {
    unsigned a = u << 16, b = u & 0xffff0000u;
    __builtin_memcpy(&lo, &a, 4); __builtin_memcpy(&hi, &b, 4);
}
__device__ __forceinline__ void unpack16(const uint4 w0, const uint4 w1, float* f) {
    unpack2(w0.x, f[0],  f[1]);  unpack2(w0.y, f[2],  f[3]);
    unpack2(w0.z, f[4],  f[5]);  unpack2(w0.w, f[6],  f[7]);
    unpack2(w1.x, f[8],  f[9]);  unpack2(w1.y, f[10], f[11]);
    unpack2(w1.z, f[12], f[13]); unpack2(w1.w, f[14], f[15]);
}

// ---------- LN param staging with fallback (gamma=1, beta=0) ----------
__global__ __launch_bounds__(128) void ln_param_kernel(
        const float* __restrict__ g, const float* __restrict__ b,
        float* __restrict__ gws, float* __restrict__ bws) {
    int k = threadIdx.x;
    gws[k] = g ? g[k] : 1.0f;
    bws[k] = b ? b[k] : 0.0f;
}

// ---------- WT prep: W -> bf16, B^T-fragment order WT[j][c][h] ----------
// c = mat*128 + n*16 + d (mat 0=Q,1=K,2=V). Q pre-scaled by 1/sqrt(HS)=0.25.
__global__ __launch_bounds__(128) void wt_prep(
        const float* __restrict__ qm, const float* __restrict__ km,
        const float* __restrict__ vm, unsigned short* __restrict__ WT) {
    int h   = threadIdx.x;          // 0..127
    int blk = blockIdx.x;           // j*384 + c
    int c = blk % 384, j = blk / 384;
    int mat = c >> 7, nd = c & 127, n = nd >> 4, d = nd & 15;
    const float* src = (mat == 0) ? qm : ((mat == 1) ? km : vm);
    float w = src[(((size_t)(n * JJ + j) * HH) + h) * HSS + d];
    if (mat == 0) w *= 0.25f;
    WT[(size_t)blk * HH + h] = f2b(w);
}

// ---------- kernel 1: QKV projection via MFMA ----------
// block = (b, j, mtile64); 4 waves, wave = 16 rows x 384 cols, K-loop 4x32.
// mfma_f32_16x16x32_bf16: A[m=lane&15][k=quad*8+j], B^T[n=lane&15][k=quad*8+j],
// C/D col=lane&15, row=quad*4+reg (HW-verified mapping).
__global__ __launch_bounds__(256, 2) void qkv_mfma(
        const float* __restrict__ x, const unsigned short* __restrict__ WT,
        unsigned short* __restrict__ Qbf, unsigned short* __restrict__ KVbf) {
    int tid = threadIdx.x;
    int blk = blockIdx.x;           // ((b*J + j)*8 + mtile)
    int mtile = blk & 7;
    int bj = blk >> 3;
    int j = bj % JJ, b = bj / JJ;
    int w = tid >> 6, lane = tid & 63, n16 = lane & 15, quad = lane >> 4;
    int m_base = mtile * 64 + w * 16;

    f32x4 acc[24];
#pragma unroll
    for (int i = 0; i < 24; ++i) acc[i] = (f32x4){0.f, 0.f, 0.f, 0.f};

    int mA = m_base + n16;          // A-operand row for this lane
    const float* xrow = x + ((size_t)(b * SS + mA) * JJ + j) * HH;
    const unsigned short* wtj = WT + (size_t)j * 384 * HH;

    for (int k0 = 0; k0 < HH; k0 += 32) {
        float4 xa = *(const float4*)(xrow + k0 + quad * 8);
        float4 xb = *(const float4*)(xrow + k0 + quad * 8 + 4);
        bf16x8 a;
        a[0] = (short)f2b(xa.x); a[1] = (short)f2b(xa.y);
        a[2] = (short)f2b(xa.z); a[3] = (short)f2b(xa.w);
        a[4] = (short)f2b(xb.x); a[5] = (short)f2b(xb.y);
        a[6] = (short)f2b(xb.z); a[7] = (short)f2b(xb.w);
#pragma unroll
        for (int c16 = 0; c16 < 24; ++c16) {
            bf16x8 bf = *(const bf16x8*)(wtj + ((size_t)(c16 * 16 + n16) * HH + k0 + quad * 8));
            acc[c16] = __builtin_amdgcn_mfma_f32_16x16x32_bf16(a, bf, acc[c16], 0, 0, 0);
        }
    }
    // epilogue: C-layout scatter to Qbf / interleaved KVbf
    int m_out = m_base + quad * 4;
#pragma unroll
    for (int c16 = 0; c16 < 24; ++c16) {
        int mat = c16 >> 3, h = c16 & 7;
        size_t rowbase = (size_t)((b * NHH + h) * JJ + j) * SS;
#pragma unroll
        for (int r = 0; r < 4; ++r) {
            unsigned short v = f2b(acc[c16][r]);
            size_t m = rowbase + m_out + r;
            if (mat == 0)      Qbf[m * 16 + n16] = v;
            else if (mat == 1) KVbf[m * 32 + n16] = v;
            else               KVbf[m * 32 + 16 + n16] = v;
        }
    }
}

// ---------- kernel 2: causal attention per (b,n,j), Q/KV precomputed ----------
// LDS: interleaved K|V bf16 32 KB. launch_bounds(256,2): VGPR cap 256 — no
// spill (cap 84 at (256,3) spilled to HBM, 3.1 GB traffic — measured round 8).
__global__ __launch_bounds__(256, 2) void attn_kernel(
        const unsigned short* __restrict__ Qbf,
        const unsigned short* __restrict__ KVbf,
        unsigned short* __restrict__ AObf) {
    __shared__ __align__(16) unsigned short KVs[SS][32];  // 32 KB
    int tid = threadIdx.x;
    int blk = blockIdx.x;           // (b*NH+n)*J + j
    int j  = blk % JJ;
    int nb = blk / JJ;
    int n  = nb % NHH;
    int b  = nb / NHH;

    // stage KV tile (coalesced uint4 copy)
    const uint4* src = (const uint4*)(KVbf + (size_t)blk * SS * 32);
    uint4* dst = (uint4*)KVs;
    for (int i = tid; i < SS * 32 / 8; i += 256) dst[i] = src[i];

    int r1 = tid;            // rows 0..255
    int r2 = SS - 1 - tid;   // rows 511..256
    const uint4* q1p = (const uint4*)(Qbf + ((size_t)blk * SS + r1) * 16);
    const uint4* q2p = (const uint4*)(Qbf + ((size_t)blk * SS + r2) * 16);
    uint4 qa = q1p[0], qb = q1p[1], qc = q2p[0], qd = q2p[1];
    float q1[16], q2[16];
    unpack16(qa, qb, q1);
    unpack16(qc, qd, q2);
    __syncthreads();

    float o1[16], o2[16];
#pragma unroll
    for (int d = 0; d < 16; ++d) { o1[d] = 0.f; o2[d] = 0.f; }
    float l1 = 0.f, l2 = 0.f;

    // phase 1: tt in [0,256): r2 >= 256 always active; r1 conditional
    for (int tt = 0; tt < 256; ++tt) {
        const uint4* kv = (const uint4*)KVs[tt];
        uint4 u0 = kv[0], u1 = kv[1], u2 = kv[2], u3 = kv[3];
        float kf[16], vf[16];
        unpack16(u0, u1, kf);
        unpack16(u2, u3, vf);
        if (tt <= r1) {
            float dp = 0.f;
#pragma unroll
            for (int d = 0; d < 16; ++d) dp = fmaf(q1[d], kf[d], dp);
            float p = __expf(fminf(dp, 60.f));
            l1 += p;
#pragma unroll
            for (int d = 0; d < 16; ++d) o1[d] = fmaf(p, vf[d], o1[d]);
        }
        {
            float dp = 0.f;
#pragma unroll
            for (int d = 0; d < 16; ++d) dp = fmaf(q2[d], kf[d], dp);
            float p = __expf(fminf(dp, 60.f));
            l2 += p;
#pragma unroll
            for (int d = 0; d < 16; ++d) o2[d] = fmaf(p, vf[d], o2[d]);
        }
    }
    // phase 2: only r2 can be active; loads inside branch (execz skip)
    for (int tt = 256; tt < SS; ++tt) {
        if (tt <= r2) {
            const uint4* kv = (const uint4*)KVs[tt];
            uint4 u0 = kv[0], u1 = kv[1], u2 = kv[2], u3 = kv[3];
            float kf[16], vf[16];
            unpack16(u0, u1, kf);
            unpack16(u2, u3, vf);
            float dp = 0.f;
#pragma unroll
            for (int d = 0; d < 16; ++d) dp = fmaf(q2[d], kf[d], dp);
            float p = __expf(fminf(dp, 60.f));
            l2 += p;
#pragma unroll
            for (int d = 0; d < 16; ++d) o2[d] = fmaf(p, vf[d], o2[d]);
        }
    }
    // AO layout: (b, s, j, n*HS+d), bf16 packed pairs
    float inv1 = 1.0f / l1, inv2 = 1.0f / l2;
    unsigned* out1 = (unsigned*)(AObf + ((size_t)((b * SS + r1) * JJ + j)) * HH + n * HSS);
    unsigned* out2 = (unsigned*)(AObf + ((size_t)((b * SS + r2) * JJ + j)) * HH + n * HSS);
#pragma unroll
    for (int d = 0; d < 8; ++d) {
        out1[d] = pk2(o1[2 * d] * inv1, o1[2 * d + 1] * inv1);
        out2[d] = pk2(o2[2 * d] * inv2, o2[2 * d + 1] * inv2);
    }
}

// ---------- kernel B: output projection + residual + LayerNorm (fp32 out) ----------
__global__ __launch_bounds__(256) void proj_ln_kernel(
        const unsigned short* __restrict__ AObf, const float* __restrict__ x,
        const float* __restrict__ proj,
        const float* __restrict__ gamma, const float* __restrict__ beta,
        float* __restrict__ out) {
    __shared__ float aoS[8][HH];        // 4 KB
    __shared__ float meanS[8], rstdS[8];
    int blk   = blockIdx.x;             // (b*J + j)*(S/8) + stile
    int stile = blk % (SS / 8);
    int t2    = blk / (SS / 8);
    int j = t2 % JJ;
    int b = t2 / JJ;
    int s0  = stile * 8;
    int tid = threadIdx.x;

    for (int i2 = tid; i2 < 512; i2 += 256) {
        int lr = i2 >> 6, kk = (i2 & 63) * 2;
        unsigned v = *(const unsigned*)(AObf + ((size_t)((b * SS + s0 + lr) * JJ + j)) * HH + kk);
        unpack2(v, aoS[lr][kk], aoS[lr][kk + 1]);
    }
    __syncthreads();

    int k  = tid & 127;
    int rg = tid >> 7;                  // rows rg, rg+2, rg+4, rg+6
    float acc[4] = {0.f, 0.f, 0.f, 0.f};
    const float* pjp = proj + (size_t)j * HH * HH;
    for (int h = 0; h < HH; ++h) {
        float w = pjp[h * HH + k];      // proj[j,h,k], coalesced over k
#pragma unroll
        for (int i = 0; i < 4; ++i) acc[i] = fmaf(aoS[rg + 2 * i][h], w, acc[i]);
    }
    float val[4];
#pragma unroll
    for (int i = 0; i < 4; ++i) {
        int srow = s0 + rg + 2 * i;
        val[i] = acc[i] + x[((size_t)((b * SS + srow) * JJ + j)) * HH + k];
    }
    __syncthreads();                    // everyone done reading aoS
#pragma unroll
    for (int i = 0; i < 4; ++i) aoS[rg + 2 * i][k] = val[i];
    __syncthreads();

    // LN reductions: 32 lanes per row
    int row = tid >> 5, l32 = tid & 31;
    float s1 = 0.f, s2 = 0.f;
#pragma unroll
    for (int c = 0; c < 4; ++c) {
        float v = aoS[row][l32 + 32 * c];
        s1 += v; s2 += v * v;
    }
#pragma unroll
    for (int mdel = 16; mdel >= 1; mdel >>= 1) {
        s1 += __shfl_xor(s1, mdel, 64);
        s2 += __shfl_xor(s2, mdel, 64);
    }
    if (l32 == 0) {
        float mu  = s1 * (1.0f / 128.0f);
        float var = s2 * (1.0f / 128.0f) - mu * mu;
        meanS[row] = mu;
        rstdS[row] = rsqrtf(var + 1e-5f);
    }
    __syncthreads();
    float g  = gamma[k];
    float bt = beta[k];
#pragma unroll
    for (int i = 0; i < 4; ++i) {
        int lr = rg + 2 * i;
        float o = (val[i] - meanS[lr]) * rstdS[lr] * g + bt;
        out[((size_t)((b * SS + s0 + lr) * JJ + j)) * HH + k] = o;
    }
}

extern "C" void kernel_launch(void* const* d_in, const int* in_sizes, int n_in,
                              void* d_out, int out_size, void* d_ws, size_t ws_size,
                              hipStream_t stream) {
    const int NX  = BB * SS * JJ * HH;     // 6,291,456
    const int NMK = SS * SS;               // 262,144
    const int NW  = NHH * JJ * HH * HSS;   // 393,216 (== JJ*HH*HH)
    const float* x = nullptr;
    const float* w4[4] = {nullptr, nullptr, nullptr, nullptr};
    const float* p128[2] = {nullptr, nullptr};
    int nW = 0, n128 = 0;
    for (int i = 0; i < n_in; ++i) {
        int s = in_sizes[i];
        const float* p = (const float*)d_in[i];
        if      (s == NX)   { if (!x) x = p; }
        else if (s == NMK)  { /* causal mask: implemented directly */ }
        else if (s == NW)   { if (nW < 4)  w4[nW++] = p; }
        else if (s == HH)   { if (n128 < 2) p128[n128++] = p; }
    }
    const float* qm = w4[0];
    const float* km = w4[1];
    const float* vm = w4[2];
    const float* pj = w4[3];
    float* out = (float*)d_out;            // reference output dtype: float32

    // ws layout (52.8 MB total):
    //   AObf  bf16 NX            (12.6 MB)
    //   gamma/beta fp32 2*128
    //   Qbf   bf16 768*512*16    (12.6 MB)
    //   KVbf  bf16 768*512*32    (25.2 MB, K|V interleaved)
    //   WT    bf16 24*384*128    ( 2.4 MB)
    unsigned short* AObf = (unsigned short*)d_ws;
    float* gb = (float*)(AObf + (size_t)NX);
    float* bb = gb + HH;
    unsigned short* Qbf  = (unsigned short*)(bb + HH);
    unsigned short* KVbf = Qbf + (size_t)BB * NHH * JJ * SS * 16;
    unsigned short* WT   = KVbf + (size_t)BB * NHH * JJ * SS * 32;

    ln_param_kernel<<<1, 128, 0, stream>>>(p128[0], p128[1], gb, bb);
    wt_prep<<<JJ * 384, 128, 0, stream>>>(qm, km, vm, WT);
    qkv_mfma<<<BB * JJ * 8, 256, 0, stream>>>(x, WT, Qbf, KVbf);
    attn_kernel<<<BB * NHH * JJ, 256, 0, stream>>>(Qbf, KVbf, AObf);
    proj_ln_kernel<<<BB * JJ * (SS / 8), 256, 0, stream>>>(AObf, x, pj, gb, bb, out);
}

// Round 11
// 219.921 us; speedup vs baseline: 4.1897x; 1.5674x over previous
//
#include <hip/hip_runtime.h>

#define BB  4
#define SS  512
#define JJ  24
#define HH  128
#define NHH 8
#define HSS 16

typedef __attribute__((ext_vector_type(8))) short bf16x8;
typedef __attribute__((ext_vector_type(4))) float f32x4;

// ---------- bf16 helpers ----------
__device__ __forceinline__ unsigned short f2b(float f) {
    unsigned u; __builtin_memcpy(&u, &f, 4);
    u += 0x7fffu + ((u >> 16) & 1u);          // RNE
    return (unsigned short)(u >> 16);
}
__device__ __forceinline__ unsigned pk2(float a, float b) {
    return (unsigned)f2b(a) | ((unsigned)f2b(b) << 16);
}
__device__ __forceinline__ void unpack2(unsigned u, float& lo, float& hi) {
    unsigned a = u << 16, b = u & 0xffff0000u;
    __builtin_memcpy(&lo, &a, 4); __builtin_memcpy(&hi, &b, 4);
}

// ---------- LN param staging with fallback (gamma=1, beta=0) ----------
__global__ __launch_bounds__(128) void ln_param_kernel(
        const float* __restrict__ g, const float* __restrict__ b,
        float* __restrict__ gws, float* __restrict__ bws) {
    int k = threadIdx.x;
    gws[k] = g ? g[k] : 1.0f;
    bws[k] = b ? b[k] : 0.0f;
}

// ---------- WT prep: W -> bf16, B^T-fragment order WT[j][c][h] ----------
// c = mat*128 + n*16 + d (mat 0=Q,1=K,2=V). Q pre-scaled by 1/sqrt(HS)=0.25.
__global__ __launch_bounds__(128) void wt_prep(
        const float* __restrict__ qm, const float* __restrict__ km,
        const float* __restrict__ vm, unsigned short* __restrict__ WT) {
    int h   = threadIdx.x;          // 0..127
    int blk = blockIdx.x;           // j*384 + c
    int c = blk % 384, j = blk / 384;
    int mat = c >> 7, nd = c & 127, n = nd >> 4, d = nd & 15;
    const float* src = (mat == 0) ? qm : ((mat == 1) ? km : vm);
    float w = src[(((size_t)(n * JJ + j) * HH) + h) * HSS + d];
    if (mat == 0) w *= 0.25f;
    WT[(size_t)blk * HH + h] = f2b(w);
}

// ---------- kernel 1: QKV projection via MFMA ----------
// block = (b, j, mtile64); 4 waves, wave = 16 rows x 384 cols, K-loop 4x32.
// Q/K written row-major [blk][512][16]; V written TRANSPOSED [blk][16][512]
// by swapping MFMA operand order for the V tiles (D = Wv^T . x = V^T).
__global__ __launch_bounds__(256, 2) void qkv_mfma(
        const float* __restrict__ x, const unsigned short* __restrict__ WT,
        unsigned short* __restrict__ Qbf, unsigned short* __restrict__ Kbf,
        unsigned short* __restrict__ Vtg) {
    int tid = threadIdx.x;
    int blk = blockIdx.x;           // ((b*J + j)*8 + mtile)
    int mtile = blk & 7;
    int bj = blk >> 3;
    int j = bj % JJ, b = bj / JJ;
    int w = tid >> 6, lane = tid & 63, n16 = lane & 15, quad = lane >> 4;
    int m_base = mtile * 64 + w * 16;

    f32x4 acc[24];
#pragma unroll
    for (int i = 0; i < 24; ++i) acc[i] = (f32x4){0.f, 0.f, 0.f, 0.f};

    int mA = m_base + n16;          // A-operand row for this lane
    const float* xrow = x + ((size_t)(b * SS + mA) * JJ + j) * HH;
    const unsigned short* wtj = WT + (size_t)j * 384 * HH;

    for (int k0 = 0; k0 < HH; k0 += 32) {
        float4 xa = *(const float4*)(xrow + k0 + quad * 8);
        float4 xb = *(const float4*)(xrow + k0 + quad * 8 + 4);
        bf16x8 a;
        a[0] = (short)f2b(xa.x); a[1] = (short)f2b(xa.y);
        a[2] = (short)f2b(xa.z); a[3] = (short)f2b(xa.w);
        a[4] = (short)f2b(xb.x); a[5] = (short)f2b(xb.y);
        a[6] = (short)f2b(xb.z); a[7] = (short)f2b(xb.w);
#pragma unroll
        for (int c16 = 0; c16 < 24; ++c16) {
            bf16x8 bf = *(const bf16x8*)(wtj + ((size_t)(c16 * 16 + n16) * HH + k0 + quad * 8));
            if (c16 < 16) acc[c16] = __builtin_amdgcn_mfma_f32_16x16x32_bf16(a, bf, acc[c16], 0, 0, 0);
            else          acc[c16] = __builtin_amdgcn_mfma_f32_16x16x32_bf16(bf, a, acc[c16], 0, 0, 0);
        }
    }
    int m_out = m_base + quad * 4;
#pragma unroll
    for (int c16 = 0; c16 < 24; ++c16) {
        int mat = c16 >> 3, h = c16 & 7;
        size_t rowbase = (size_t)((b * NHH + h) * JJ + j) * SS;
#pragma unroll
        for (int r = 0; r < 4; ++r) {
            unsigned short v = f2b(acc[c16][r]);
            if (mat == 0)      Qbf[(rowbase + m_out + r) * 16 + n16] = v;
            else if (mat == 1) Kbf[(rowbase + m_out + r) * 16 + n16] = v;
            else {
                // V^T: lane holds V^T[d=quad*4+r][m=m_base+n16]
                Vtg[(rowbase + (size_t)0) * 16 + (size_t)(quad * 4 + r) * SS + m_base + n16] = v;
            }
        }
    }
}

// ---------- kernel 2: MFMA flash attention per (b,n,j) ----------
// 4 waves; wave w owns Q-tiles t = w, w+4, ..., w+28 (causal-balanced).
// Scores computed TRANSPOSED (S^T = K.Q^T) so the exp'd P^T C-fragment is one
// wave-private LDS round-trip away from the PV A-operand fragment; PV at K=32.
__global__ __launch_bounds__(256, 2) void attn_kernel(
        const unsigned short* __restrict__ Qbf,
        const unsigned short* __restrict__ Kbf,
        const unsigned short* __restrict__ Vtg,
        unsigned short* __restrict__ AObf) {
    __shared__ __align__(16) unsigned short Ks[SS][24];   // 24.0 KB (pad: 2-way max)
    __shared__ __align__(16) unsigned short Vt[16][520];  // 16.3 KB (pad: 2-way max)
    __shared__ __align__(16) unsigned short Pl[4][16][40];// 5.0 KB wave-private P
    int tid = threadIdx.x;
    int blk = blockIdx.x;           // (b*NH+n)*J + j
    int j  = blk % JJ;
    int nb = blk / JJ;
    int n  = nb % NHH;
    int b  = nb / NHH;
    int w = tid >> 6, lane = tid & 63, m = lane & 15, q = lane >> 4;

    // stage K rows and V^T rows (both coalesced uint4)
    const unsigned short* kg = Kbf + (size_t)blk * SS * 16;
    const unsigned short* vg = Vtg + (size_t)blk * SS * 16;
    for (int ci = tid; ci < 1024; ci += 256) {
        int c = ci >> 1, half = ci & 1;
        *(uint4*)&Ks[c][half * 8] = *(const uint4*)(kg + c * 16 + half * 8);
        int d = ci >> 6, cpos = (ci & 63) * 8;
        *(uint4*)&Vt[d][cpos] = *(const uint4*)(vg + d * SS + cpos);
    }
    __syncthreads();

    const unsigned short* qg = Qbf + (size_t)blk * SS * 16;
    const bf16x8 zf = {0, 0, 0, 0, 0, 0, 0, 0};
    const f32x4 z4 = {0.f, 0.f, 0.f, 0.f};

    for (int t8 = 0; t8 < 8; ++t8) {
        int t = w + t8 * 4;
        // Q B-operand fragment: lane(q,m) = Q[t*16+m][d=q*8+i], zero for q>=2
        bf16x8 qf = zf;
        if (q < 2) qf = *(const bf16x8*)(qg + (t * 16 + m) * 16 + q * 8);

        f32x4 acc = z4;
        float l = 0.f;
        int nblk = (t >> 1) + 1;
        int mg = t * 16 + m;
        for (int cb = 0; cb < nblk; ++cb) {
            // K A-operand fragments for tiles 2cb, 2cb+1
            bf16x8 kf0 = zf, kf1 = zf;
            if (q < 2) {
                kf0 = *(const bf16x8*)&Ks[cb * 32 + m][q * 8];
                kf1 = *(const bf16x8*)&Ks[cb * 32 + 16 + m][q * 8];
            }
            f32x4 s0 = __builtin_amdgcn_mfma_f32_16x16x32_bf16(kf0, qf, z4, 0, 0, 0);
            f32x4 s1 = __builtin_amdgcn_mfma_f32_16x16x32_bf16(kf1, qf, z4, 0, 0, 0);
            // exp (no-max softmax, validated r8-r10) + causal mask on last block
            float p0[4], p1[4];
            if (cb == nblk - 1) {
#pragma unroll
                for (int r = 0; r < 4; ++r) {
                    int cg0 = cb * 32 + q * 4 + r;
                    p0[r] = (cg0      <= mg) ? __expf(fminf(s0[r], 60.f)) : 0.f;
                    p1[r] = (cg0 + 16 <= mg) ? __expf(fminf(s1[r], 60.f)) : 0.f;
                }
            } else {
#pragma unroll
                for (int r = 0; r < 4; ++r) {
                    p0[r] = __expf(fminf(s0[r], 60.f));
                    p1[r] = __expf(fminf(s1[r], 60.f));
                }
            }
            l += (p0[0] + p0[1]) + (p0[2] + p0[3]) + (p1[0] + p1[1]) + (p1[2] + p1[3]);
            // P^T C-layout -> PV A-layout via wave-private LDS (DS wave-ordered)
            unsigned short* plm = &Pl[w][m][0];
            *(unsigned*)(plm + q * 4)      = pk2(p0[0], p0[1]);
            *(unsigned*)(plm + q * 4 + 2)  = pk2(p0[2], p0[3]);
            *(unsigned*)(plm + 16 + q * 4)     = pk2(p1[0], p1[1]);
            *(unsigned*)(plm + 16 + q * 4 + 2) = pk2(p1[2], p1[3]);
            bf16x8 pf = *(const bf16x8*)(plm + q * 8);
            // V B-operand: lane(q,d=m) = V^T[d][c=cb*32+q*8+i]
            bf16x8 vf = *(const bf16x8*)&Vt[m][cb * 32 + q * 8];
            acc = __builtin_amdgcn_mfma_f32_16x16x32_bf16(pf, vf, acc, 0, 0, 0);
        }
        // row-sums: reduce l across quads; all lanes end with l[their m]
        l += __shfl_xor(l, 16);
        l += __shfl_xor(l, 32);
        // output: lane(q,d=m) holds O[row=q*4+r][d]; l for row via shfl
#pragma unroll
        for (int r = 0; r < 4; ++r) {
            float lr = __shfl(l, q * 4 + r);
            int srow = t * 16 + q * 4 + r;
            AObf[((size_t)(b * SS + srow) * JJ + j) * HH + n * HSS + m] =
                f2b(acc[r] / lr);
        }
    }
}

// ---------- kernel B: output projection + residual + LayerNorm (fp32 out) ----------
__global__ __launch_bounds__(256) void proj_ln_kernel(
        const unsigned short* __restrict__ AObf, const float* __restrict__ x,
        const float* __restrict__ proj,
        const float* __restrict__ gamma, const float* __restrict__ beta,
        float* __restrict__ out) {
    __shared__ float aoS[8][HH];        // 4 KB
    __shared__ float meanS[8], rstdS[8];
    int blk   = blockIdx.x;             // (b*J + j)*(S/8) + stile
    int stile = blk % (SS / 8);
    int t2    = blk / (SS / 8);
    int j = t2 % JJ;
    int b = t2 / JJ;
    int s0  = stile * 8;
    int tid = threadIdx.x;

    for (int i2 = tid; i2 < 512; i2 += 256) {
        int lr = i2 >> 6, kk = (i2 & 63) * 2;
        unsigned v = *(const unsigned*)(AObf + ((size_t)((b * SS + s0 + lr) * JJ + j)) * HH + kk);
        unpack2(v, aoS[lr][kk], aoS[lr][kk + 1]);
    }
    __syncthreads();

    int k  = tid & 127;
    int rg = tid >> 7;                  // rows rg, rg+2, rg+4, rg+6
    float acc[4] = {0.f, 0.f, 0.f, 0.f};
    const float* pjp = proj + (size_t)j * HH * HH;
    for (int h = 0; h < HH; ++h) {
        float w = pjp[h * HH + k];      // proj[j,h,k], coalesced over k
#pragma unroll
        for (int i = 0; i < 4; ++i) acc[i] = fmaf(aoS[rg + 2 * i][h], w, acc[i]);
    }
    float val[4];
#pragma unroll
    for (int i = 0; i < 4; ++i) {
        int srow = s0 + rg + 2 * i;
        val[i] = acc[i] + x[((size_t)((b * SS + srow) * JJ + j)) * HH + k];
    }
    __syncthreads();
#pragma unroll
    for (int i = 0; i < 4; ++i) aoS[rg + 2 * i][k] = val[i];
    __syncthreads();

    int row = tid >> 5, l32 = tid & 31;
    float s1 = 0.f, s2 = 0.f;
#pragma unroll
    for (int c = 0; c < 4; ++c) {
        float v = aoS[row][l32 + 32 * c];
        s1 += v; s2 += v * v;
    }
#pragma unroll
    for (int mdel = 16; mdel >= 1; mdel >>= 1) {
        s1 += __shfl_xor(s1, mdel, 64);
        s2 += __shfl_xor(s2, mdel, 64);
    }
    if (l32 == 0) {
        float mu  = s1 * (1.0f / 128.0f);
        float var = s2 * (1.0f / 128.0f) - mu * mu;
        meanS[row] = mu;
        rstdS[row] = rsqrtf(var + 1e-5f);
    }
    __syncthreads();
    float g  = gamma[k];
    float bt = beta[k];
#pragma unroll
    for (int i = 0; i < 4; ++i) {
        int lr = rg + 2 * i;
        float o = (val[i] - meanS[lr]) * rstdS[lr] * g + bt;
        out[((size_t)((b * SS + s0 + lr) * JJ + j)) * HH + k] = o;
    }
}

extern "C" void kernel_launch(void* const* d_in, const int* in_sizes, int n_in,
                              void* d_out, int out_size, void* d_ws, size_t ws_size,
                              hipStream_t stream) {
    const int NX  = BB * SS * JJ * HH;     // 6,291,456
    const int NMK = SS * SS;               // 262,144
    const int NW  = NHH * JJ * HH * HSS;   // 393,216 (== JJ*HH*HH)
    const float* x = nullptr;
    const float* w4[4] = {nullptr, nullptr, nullptr, nullptr};
    const float* p128[2] = {nullptr, nullptr};
    int nW = 0, n128 = 0;
    for (int i = 0; i < n_in; ++i) {
        int s = in_sizes[i];
        const float* p = (const float*)d_in[i];
        if      (s == NX)   { if (!x) x = p; }
        else if (s == NMK)  { /* causal mask: implemented directly */ }
        else if (s == NW)   { if (nW < 4)  w4[nW++] = p; }
        else if (s == HH)   { if (n128 < 2) p128[n128++] = p; }
    }
    const float* qm = w4[0];
    const float* km = w4[1];
    const float* vm = w4[2];
    const float* pj = w4[3];
    float* out = (float*)d_out;            // reference output dtype: float32

    // ws layout (52.8 MB total): AObf | gamma/beta | Qbf | Kbf | Vtg | WT
    const size_t NQ = (size_t)BB * NHH * JJ * SS * 16;   // 6.29M ushorts each
    unsigned short* AObf = (unsigned short*)d_ws;
    float* gb = (float*)(AObf + (size_t)NX);
    float* bb = gb + HH;
    unsigned short* Qbf = (unsigned short*)(bb + HH);
    unsigned short* Kbf = Qbf + NQ;
    unsigned short* Vtg = Kbf + NQ;
    unsigned short* WT  = Vtg + NQ;

    ln_param_kernel<<<1, 128, 0, stream>>>(p128[0], p128[1], gb, bb);
    wt_prep<<<JJ * 384, 128, 0, stream>>>(qm, km, vm, WT);
    qkv_mfma<<<BB * JJ * 8, 256, 0, stream>>>(x, WT, Qbf, Kbf, Vtg);
    attn_kernel<<<BB * NHH * JJ, 256, 0, stream>>>(Qbf, Kbf, Vtg, AObf);
    proj_ln_kernel<<<BB * JJ * (SS / 8), 256, 0, stream>>>(AObf, x, pj, gb, bb, out);
}